// Round 8
// baseline (318.038 us; speedup 1.0000x reference)
//
#include <hip/hip_runtime.h>
#include <hip/hip_cooperative_groups.h>
#include <stdint.h>

namespace cg = cooperative_groups;

// Match reference numerics: no FMA contraction anywhere (discrete IoU>thres
// decisions flip on 1-ulp differences).
#pragma clang fp contract(off)

#define BATCH 32
#define NPRED 25200
#define ROWF 9
#define TOPK 1000
#define SUBS 8
#define ROWS_PER_SUB (NPRED / SUBS)   // 3150
#define SUBCAP 512
#define CONF_T 0.7f
#define IOU_T 0.45f
#define KW 16          // 1000 bits -> 16 u64 words
#define SUPROW 1024    // global sup stride per word-column
#define TKROW 1024     // tkey stride per image

typedef unsigned long long u64;
typedef unsigned int u32;

// ---- workspace layout (bytes) ----
#define WS_CAND 0                      // 256 lists x 512 u64 = 1,048,576
#define WS_TKEY (1048576)              // 32 x 1024 u64       =   262,144
#define WS_SUP  (WS_TKEY + 262144)     // 32 x 16 x 1024 u64  = 4,194,304

__device__ __forceinline__ u64 readlane64(u64 v, int l) {
    // wave-uniform lane index -> v_readlane_b32 x2 (VALU, no LDS pipe)
    u32 lo = __builtin_amdgcn_readlane((u32)v, (u32)l);
    u32 hi = __builtin_amdgcn_readlane((u32)(v >> 32), (u32)l);
    return ((u64)hi << 32) | lo;
}

// Single cooperative kernel, 256 blocks x 512 threads, 3 grid syncs.
// P1 compact+sort (block = image x sub-range) -> cand_ws
// P2 rank-merge (same mapping) -> tkey_ws scatter
// P3 suppression matrix (8 blocks/image, 136 upper-tri 64x64 tiles) -> sup_g
// P4 sparse register greedy scan + output (blocks 0..31, wave owns 2 columns)
__global__ __launch_bounds__(512) void mega_kernel(const float* __restrict__ pred,
                                                   u64* __restrict__ cand_ws,
                                                   u64* __restrict__ tkey_ws,
                                                   u64* __restrict__ sup_g,
                                                   float* __restrict__ out,
                                                   float* __restrict__ keepout) {
    cg::grid_group grid = cg::this_grid();
    __shared__ u64 smem[SUBS * SUBCAP];   // 32 KB arena, re-carved per phase
    __shared__ u32 cnt;
    __shared__ u64 acc_lds;
    __shared__ u64 keep_sh[KW];

    int bs = blockIdx.x;          // 0..255
    int b = bs >> 3, s = bs & 7;
    int tid = threadIdx.x;

    // ================= P1: compact + in-block bitonic sort =================
    // key = (float_bits(conf)<<32) | ~row -> desc order == (score desc, idx
    // asc), exactly jax.lax.top_k tie-breaking. ~317 valid/3150 expected;
    // SUBCAP=512 is mean+11.5 sigma. Also zeroes tkey_ws (0xAA-poisoned).
    {
        float* stage = (float*)smem;      // 18432 B
        u64* skey = smem + 2304;          // 4096 B
        if (tid == 0) cnt = 0;
        skey[tid] = 0;
        if (tid < 128) tkey_ws[bs * 128 + tid] = 0;   // 256 x 128 = 32 x 1024
        __syncthreads();
        int r0 = s * ROWS_PER_SUB;
        for (int c0 = 0; c0 < ROWS_PER_SUB; c0 += 512) {
            int nrows = ROWS_PER_SUB - c0; if (nrows > 512) nrows = 512;
            int nfl = nrows * ROWF;
            size_t g0 = ((size_t)b * NPRED + r0 + c0) * ROWF;
            // cooperative copy, float4 body + peel
            int h = (int)((4 - (g0 & 3)) & 3); if (h > nfl) h = nfl;
            if (tid < h) stage[tid] = pred[g0 + tid];
            int nv = (nfl - h) >> 2;
            const float4* pv = (const float4*)(pred + g0 + h);
            for (int v = tid; v < nv; v += 512) {
                float4 q = pv[v];
                int d = h + v * 4;
                stage[d] = q.x; stage[d + 1] = q.y; stage[d + 2] = q.z; stage[d + 3] = q.w;
            }
            for (int t2 = h + nv * 4 + tid; t2 < nfl; t2 += 512) stage[t2] = pred[g0 + t2];
            __syncthreads();
            if (tid < nrows) {
                float obj = stage[tid * ROWF + 4];
                float cls = stage[tid * ROWF + 5];
                float conf = obj * cls;
                if (obj > CONF_T && conf > CONF_T) {
                    int r = r0 + c0 + tid;
                    u32 slot = atomicAdd(&cnt, 1u);
                    if (slot < SUBCAP)
                        skey[slot] = ((u64)__float_as_uint(conf) << 32) | (u64)(u32)(~(u32)r);
                }
            }
            __syncthreads();
        }
        // bitonic sort, descending, 512 elements (45 passes)
        for (int k = 2; k <= SUBCAP; k <<= 1) {
            for (int j = k >> 1; j > 0; j >>= 1) {
                int t = tid, p = t ^ j;
                if (p > t) {
                    u64 a = skey[t], c2 = skey[p];
                    bool desc = ((t & k) == 0);
                    if (desc ? (a < c2) : (a > c2)) { skey[t] = c2; skey[p] = a; }
                }
                __syncthreads();
            }
        }
        cand_ws[(size_t)bs * SUBCAP + tid] = skey[tid];
    }
    __threadfence();
    grid.sync();

    // ================= P2: rank-merge, scatter top-1000 =================
    // rank(key) = sum over all 8 sorted lists of count(> key); own list
    // contributes the key's own index (keys unique). Breadth-interleaved
    // pow2 ladder: 10 rounds x 8 independent LDS probes.
    {
        u64* lists = smem;                // 32 KB
        const u64* src = cand_ws + (size_t)b * SUBS * SUBCAP;
        for (int t = tid; t < SUBS * SUBCAP; t += 512) lists[t] = src[t];
        __syncthreads();
        u64 key = lists[(s << 9) + tid];
        if (key) {
            int lo[SUBS];
#pragma unroll
            for (int l = 0; l < SUBS; ++l) lo[l] = 0;
#pragma unroll
            for (int w2 = SUBCAP; w2 >= 1; w2 >>= 1) {
#pragma unroll
                for (int l = 0; l < SUBS; ++l) {
                    int p = lo[l] + w2;
                    if (p <= SUBCAP && lists[(l << 9) + p - 1] > key) lo[l] = p;
                }
            }
            int rank = 0;
#pragma unroll
            for (int l = 0; l < SUBS; ++l) rank += lo[l];
            if (rank < TOPK) tkey_ws[(size_t)b * TKROW + rank] = key;
        }
    }
    __threadfence();
    grid.sync();

    // ================= P3: suppression matrix =================
    {
        float4* bx_s = (float4*)smem;           // 16000 B
        float* ar_s = (float*)(smem + 2000);    // 4000 B
        for (int t = tid; t < TOPK; t += 512) {
            u64 key = tkey_ws[(size_t)b * TKROW + t];
            float4 box = make_float4(0.f, 0.f, 0.f, 0.f);
            float ar = 0.f;
            if (key) {
                u32 r = ~(u32)key;
                const float* p = pred + ((size_t)b * NPRED + r) * ROWF;
                float x = p[0], y = p[1], w = p[2], hh = p[3];
                box = make_float4(x - w * 0.5f, y - hh * 0.5f, x + w * 0.5f, y + hh * 0.5f);
                ar = (box.z - box.x) * (box.w - box.y);
            }
            bx_s[t] = box; ar_s[t] = ar;
        }
        __syncthreads();
        int w = tid >> 6, lane = tid & 63;
        int gw = (s << 3) + w;                  // 0..63 across the image's 8 blocks
        for (int ti = 0; ti < 3; ++ti) {
            int t = gw + (ti << 6);
            if (t >= 136) break;
            // decode tile t -> (iw, jw), jw >= iw
            int iw = 0, rem = t, c = 16;
            while (rem >= c) { rem -= c; c--; iw++; }
            int jw = iw + rem;
            int i = iw * 64 + lane;
            bool act = i < TOPK;
            float4 bi = act ? bx_s[i] : make_float4(0.f, 0.f, 0.f, 0.f);
            float ai = act ? ar_s[i] : 0.f;
            u64 m = 0;
            int jbase = jw << 6;
            int jend = jbase + 64; if (jend > TOPK) jend = TOPK;
            for (int j = jbase; j < jend; ++j) {
                float4 bj = bx_s[j];            // broadcast
                float aj = ar_s[j];             // broadcast
                float lx = fmaxf(bi.x, bj.x);
                float ly = fmaxf(bi.y, bj.y);
                float rx = fminf(bi.z, bj.z);
                float ry = fminf(bi.w, bj.w);
                float iw2 = rx - lx; iw2 = iw2 > 0.f ? iw2 : 0.f;
                float ih = ry - ly; ih = ih > 0.f ? ih : 0.f;
                float inter = iw2 * ih;
                float den = ai + aj - inter + 1e-7f;  // ((ai+aj)-inter)+eps, ref order
                float iou = inter / den;
                if (act && j > i && iou > IOU_T) m |= 1ull << (j - jbase);
            }
            if (act) sup_g[((size_t)b * KW + jw) * SUPROW + i] = m;
        }
    }
    __threadfence();
    grid.sync();

    // ================= P4: sparse greedy scan + output (32 blocks) =========
    if (bs < BATCH) {
        int bb = bs;
        int w = tid >> 6, lane = tid & 63;
        int cA = w, cB = w + 8;                 // this wave's two word-columns
        const u64* S = sup_g + (size_t)bb * KW * SUPROW;

        u64 keyA = tkey_ws[(size_t)bb * TKROW + tid];        // row tid
        u64 keyB = tkey_ws[(size_t)bb * TKROW + 512 + tid];  // row tid+512
        u64 k0A = __ballot(keyA != 0ull);
        u64 k0B = __ballot(keyB != 0ull);
        if (lane == 0) { keep_sh[w] = k0A; keep_sh[w + 8] = k0B; }

        u64 regA[8], regB[KW];
#pragma unroll
        for (int bi = 0; bi < 8; ++bi)
            regA[bi] = S[(size_t)cA * SUPROW + (bi << 6) + lane];  // bi>=cA: garbage, gated
#pragma unroll
        for (int bi = 0; bi < KW; ++bi)
            regB[bi] = S[(size_t)cB * SUPROW + (bi << 6) + lane];  // bi>=cB: garbage, gated
        u64 diagA = S[(size_t)cA * SUPROW + (cA << 6) + lane];
        u64 diagB = S[(size_t)cB * SUPROW + (cB << 6) + lane];
        __syncthreads();
        u64 nzA = __ballot(diagA != 0ull);
        u64 nzB = __ballot(diagB != 0ull);

#pragma unroll
        for (int bi = 0; bi < KW; ++bi) {
            if (w == (bi & 7)) {
                // serial greedy within word bi; only suppressor rows enter
                u64 diag = (bi < 8) ? diagA : diagB;   // bi compile-time
                u64 nz = (bi < 8) ? nzA : nzB;
                u64 cur = keep_sh[bi];
                u64 active = cur & nz;
                while (active) {
                    int i = __ffsll((long long)active) - 1;
                    u64 wi = readlane64(diag, i);      // row i's mask (bits>i only)
                    active &= active - 1;
                    cur &= ~wi;
                    active &= ~wi;                     // suppressed can't suppress
                }
                if (lane == 0) { keep_sh[bi] = cur; acc_lds = cur; }
            }
            __syncthreads();
            u64 A = acc_lds;                           // accepted set of block bi
            bool accb = ((A >> lane) & 1ull) != 0;
            if (bi < 8 && cA > bi) {                   // wave-uniform guards
                u64 myv = regA[bi];
                u64 lanes = __ballot(accb && myv != 0ull);
                if (lanes) {
                    u64 wred = 0;
                    while (lanes) {
                        int l = __ffsll((long long)lanes) - 1;
                        wred |= readlane64(myv, l);
                        lanes &= lanes - 1;
                    }
                    if (lane == 0) keep_sh[cA] &= ~wred;
                }
            }
            if (cB > bi) {
                u64 myv = regB[bi];
                u64 lanes = __ballot(accb && myv != 0ull);
                if (lanes) {
                    u64 wred = 0;
                    while (lanes) {
                        int l = __ffsll((long long)lanes) - 1;
                        wred |= readlane64(myv, l);
                        lanes &= lanes - 1;
                    }
                    if (lane == 0) keep_sh[cB] &= ~wred;
                }
            }
            __syncthreads();
        }

#pragma unroll
        for (int pass = 0; pass < 2; ++pass) {
            int row = tid + (pass << 9);
            u64 key = pass ? keyB : keyA;
            if (row < TOPK) {
                bool kp = ((keep_sh[row >> 6] >> (row & 63)) & 1ull) != 0;
                float o0 = 0.f, o1 = 0.f, o2 = 0.f, o3 = 0.f, o4 = 0.f, o6 = 0.f, o7 = 0.f, o8 = 0.f;
                if (kp) {
                    u32 r = ~(u32)key;
                    const float* p = pred + ((size_t)bb * NPRED + r) * ROWF;
                    float x = p[0], y = p[1], wd = p[2], hh = p[3];
                    o0 = x - wd * 0.5f; o1 = y - hh * 0.5f;
                    o2 = x + wd * 0.5f; o3 = y + hh * 0.5f;
                    o4 = __uint_as_float((u32)(key >> 32));
                    o6 = p[6]; o7 = p[7]; o8 = p[8];
                }
                size_t ob = ((size_t)bb * TOPK + row) * ROWF;
                out[ob + 0] = o0; out[ob + 1] = o1; out[ob + 2] = o2; out[ob + 3] = o3;
                out[ob + 4] = o4; out[ob + 5] = 0.f;
                out[ob + 6] = o6; out[ob + 7] = o7; out[ob + 8] = o8;
                keepout[(size_t)bb * TOPK + row] = kp ? 1.0f : 0.0f;
            }
        }
    }
}

extern "C" void kernel_launch(void* const* d_in, const int* in_sizes, int n_in,
                              void* d_out, int out_size, void* d_ws, size_t ws_size,
                              hipStream_t stream) {
    const float* pred = (const float*)d_in[0];
    float* out = (float*)d_out;                         // [32,1000,9]
    float* keepout = out + (size_t)BATCH * TOPK * ROWF; // [32,1000]
    char* ws = (char*)d_ws;
    u64* cand_ws = (u64*)(ws + WS_CAND);
    u64* tkey_ws = (u64*)(ws + WS_TKEY);
    u64* sup_g = (u64*)(ws + WS_SUP);

    void* args[] = { (void*)&pred, (void*)&cand_ws, (void*)&tkey_ws,
                     (void*)&sup_g, (void*)&out, (void*)&keepout };
    hipLaunchCooperativeKernel((void*)mega_kernel, dim3(BATCH * SUBS), dim3(512),
                               args, 0, stream);
}

// Round 9
// 225.074 us; speedup vs baseline: 1.4130x; 1.4130x over previous
//
#include <hip/hip_runtime.h>
#include <stdint.h>

// Match reference numerics: no FMA contraction anywhere (discrete IoU>thres
// decisions flip on 1-ulp differences).
#pragma clang fp contract(off)

#define BATCH 32
#define NPRED 25200
#define ROWF 9
#define TOPK 1000
#define SUBS 8
#define ROWS_PER_SUB (NPRED / SUBS)   // 3150
#define SUBCAP 512
#define CONF_T 0.7f
#define IOU_T 0.45f
#define KW 16          // 1000 bits -> 16 u64 words
#define TKROW 1024     // tkey stride per image
#define LSTRIDE 1001   // LDS sup stride (odd -> conflict-free column access)

typedef unsigned long long u64;
typedef unsigned int u32;

// ---- workspace layout (bytes) ----
#define WS_CAND 0                      // 256 lists x 512 u64 = 1,048,576
#define WS_TKEY (1048576)              // 32 x 1024 u64       =   262,144

__device__ __forceinline__ u64 readlane64(u64 v, int l) {
    // wave-uniform lane index -> v_readlane_b32 x2 (VALU, no LDS pipe)
    u32 lo = __builtin_amdgcn_readlane((u32)v, (u32)l);
    u32 hi = __builtin_amdgcn_readlane((u32)(v >> 32), (u32)l);
    return ((u64)hi << 32) | lo;
}

// K1: compact valid rows of one (image, sub-range) into keys, then bitonic-sort
// the 512-entry sub-list in-block (descending; zeros pad to the end).
// key = (float_bits(conf)<<32) | ~row  -> desc order == (score desc, idx asc),
// exactly jax.lax.top_k tie-breaking. ~317 valid rows per 3150 expected;
// SUBCAP=512 is mean+11.5 sigma. Also zeroes this block's slice of tkey_ws
// (0xAA-poisoned; rank_kernel only writes slots with rank<TOPK).
// NOTE (R8 post-mortem): do NOT fuse these phases with grid.sync() —
// cooperative grid sync costs ~60+ us on this stack vs ~6 us per launch.
__global__ __launch_bounds__(512) void compact_sort_kernel(const float* __restrict__ pred,
                                                           u64* __restrict__ cand_ws,
                                                           u64* __restrict__ tkey_ws) {
    __shared__ float stage[512 * ROWF];   // 18432 B
    __shared__ u64 skey[SUBCAP];          // 4096 B
    __shared__ u32 cnt;
    int bs = blockIdx.x;          // 0..255
    int b = bs >> 3, s = bs & 7;
    int tid = threadIdx.x;
    if (tid == 0) cnt = 0;
    skey[tid] = 0;
    if (tid < 128) tkey_ws[bs * 128 + tid] = 0;   // 256 blocks x 128 = 32 x 1024
    __syncthreads();
    int r0 = s * ROWS_PER_SUB;
    for (int c0 = 0; c0 < ROWS_PER_SUB; c0 += 512) {
        int nrows = ROWS_PER_SUB - c0; if (nrows > 512) nrows = 512;
        int nfl = nrows * ROWF;
        size_t g0 = ((size_t)b * NPRED + r0 + c0) * ROWF;  // global float index
        // cooperative copy pred[g0 .. g0+nfl) -> stage[0..nfl), float4 body + peel
        int h = (int)((4 - (g0 & 3)) & 3); if (h > nfl) h = nfl;
        if (tid < h) stage[tid] = pred[g0 + tid];
        int nv = (nfl - h) >> 2;
        const float4* pv = (const float4*)(pred + g0 + h);
        for (int v = tid; v < nv; v += 512) {
            float4 q = pv[v];
            int d = h + v * 4;
            stage[d] = q.x; stage[d + 1] = q.y; stage[d + 2] = q.z; stage[d + 3] = q.w;
        }
        for (int t2 = h + nv * 4 + tid; t2 < nfl; t2 += 512) stage[t2] = pred[g0 + t2];
        __syncthreads();
        if (tid < nrows) {
            float obj = stage[tid * ROWF + 4];
            float cls = stage[tid * ROWF + 5];
            float conf = obj * cls;
            if (obj > CONF_T && conf > CONF_T) {
                int r = r0 + c0 + tid;
                u32 slot = atomicAdd(&cnt, 1u);
                if (slot < SUBCAP)
                    skey[slot] = ((u64)__float_as_uint(conf) << 32) | (u64)(u32)(~(u32)r);
            }
        }
        __syncthreads();
    }
    // bitonic sort, descending, 512 elements, 512 threads (45 passes)
    for (int k = 2; k <= SUBCAP; k <<= 1) {
        for (int j = k >> 1; j > 0; j >>= 1) {
            int t = tid, p = t ^ j;
            if (p > t) {
                u64 a = skey[t], c2 = skey[p];
                bool desc = ((t & k) == 0);
                if (desc ? (a < c2) : (a > c2)) { skey[t] = c2; skey[p] = a; }
            }
            __syncthreads();
        }
    }
    cand_ws[(size_t)bs * SUBCAP + tid] = skey[tid];
}

// K2: rank, 8 blocks per image. Each block loads the image's full 8x512 key
// set and ranks its own sub-list's 512 keys: rank(key) = sum over all 8 lists
// of count(elements > key); own list's search returns the key's own index
// (keys unique). Breadth-interleaved pow2 ladder: 10 rounds x 8 independent
// LDS probes. Keys with rank < TOPK scatter to tkey_ws[b][rank].
__global__ __launch_bounds__(512) void rank_kernel(const u64* __restrict__ cand_ws,
                                                   u64* __restrict__ tkey_ws) {
    __shared__ u64 lists[SUBS * SUBCAP];   // 32 KB
    int bs = blockIdx.x;          // 0..255
    int b = bs >> 3, s = bs & 7;
    int tid = threadIdx.x;
    const u64* src = cand_ws + (size_t)b * SUBS * SUBCAP;
    for (int t = tid; t < SUBS * SUBCAP; t += 512) lists[t] = src[t];
    __syncthreads();
    u64 key = lists[(s << 9) + tid];
    if (key) {
        int lo[SUBS];
#pragma unroll
        for (int l = 0; l < SUBS; ++l) lo[l] = 0;
#pragma unroll
        for (int w2 = SUBCAP; w2 >= 1; w2 >>= 1) {   // 10 rounds
#pragma unroll
            for (int l = 0; l < SUBS; ++l) {
                int p = lo[l] + w2;
                if (p <= SUBCAP && lists[(l << 9) + p - 1] > key) lo[l] = p;
            }
        }
        int rank = 0;
#pragma unroll
        for (int l = 0; l < SUBS; ++l) rank += lo[l];
        if (rank < TOPK) tkey_ws[(size_t)b * TKROW + rank] = key;
    }
}

// K3 (fused supmat + scan + output), one 1024-thread block per image.
// Phase A: gather top-1000 rows, boxes/areas -> LDS; keep0 from key!=0 ballot.
// Phase B: 136 upper-tri 64x64 suppression tiles -> supc in LDS (stride 1001,
//          conflict-free; j wave-uniform -> broadcast reads; one write/tile-row).
// Phase C: sparse register greedy scan (ballot-gated suppressor rows, VALU
//          readlane broadcasts -- no LDS pipe in the serial chain).
// Phase D: gather kept rows, write output + keep mask.
__global__ __launch_bounds__(1024) void supscan_kernel(const float* __restrict__ pred,
                                                       const u64* __restrict__ tkey_ws,
                                                       float* __restrict__ out,
                                                       float* __restrict__ keepout) {
    __shared__ u64 supc[KW * LSTRIDE];   // 128128 B
    __shared__ float4 bx_s[TOPK];        // 16000 B
    __shared__ float  ar_s[TOPK];        // 4000 B
    __shared__ u64 keep_sh[KW];
    __shared__ u64 acc_lds;
    int b = blockIdx.x, tid = threadIdx.x;
    int w = tid >> 6, lane = tid & 63;

    // ---- A: top-1000 gather (rows 1000..1023 of tkey_ws are zero) ----
    u64 key = tkey_ws[(size_t)b * TKROW + tid];
    {
        float4 box = make_float4(0.f, 0.f, 0.f, 0.f);
        float ar = 0.f;
        if (key) {
            u32 r = ~(u32)key;
            const float* p = pred + ((size_t)b * NPRED + r) * ROWF;
            float x = p[0], y = p[1], wd = p[2], hh = p[3];
            box = make_float4(x - wd * 0.5f, y - hh * 0.5f, x + wd * 0.5f, y + hh * 0.5f);
            ar = (box.z - box.x) * (box.w - box.y);
        }
        if (tid < TOPK) { bx_s[tid] = box; ar_s[tid] = ar; }
        u64 k0 = __ballot(key != 0ull);
        if (lane == 0) keep_sh[w] = k0;
    }
    __syncthreads();

    // ---- B: suppression tiles into LDS ----
    for (int t = w; t < 136; t += 16) {
        // decode tile t -> (iw, jw), jw >= iw
        int iw = 0, rem = t, c = 16;
        while (rem >= c) { rem -= c; c--; iw++; }
        int jw = iw + rem;
        int i = iw * 64 + lane;
        bool act = i < TOPK;
        float4 bi = act ? bx_s[i] : make_float4(0.f, 0.f, 0.f, 0.f);
        float ai = act ? ar_s[i] : 0.f;
        u64 m = 0;
        int jbase = jw << 6;
        int jend = jbase + 64; if (jend > TOPK) jend = TOPK;
        for (int j = jbase; j < jend; ++j) {
            float4 bj = bx_s[j];            // broadcast
            float aj = ar_s[j];             // broadcast
            float lx = fmaxf(bi.x, bj.x);
            float ly = fmaxf(bi.y, bj.y);
            float rx = fminf(bi.z, bj.z);
            float ry = fminf(bi.w, bj.w);
            float iw2 = rx - lx; iw2 = iw2 > 0.f ? iw2 : 0.f;
            float ih = ry - ly; ih = ih > 0.f ? ih : 0.f;
            float inter = iw2 * ih;
            float den = ai + aj - inter + 1e-7f;  // ((ai+aj)-inter)+eps, ref order
            float iou = inter / den;
            if (act && j > i && iou > IOU_T) m |= 1ull << (j - jbase);
        }
        if (act) supc[jw * LSTRIDE + i] = m;
    }
    __syncthreads();

    // ---- C: sparse greedy scan; wave w owns word-column w ----
    u64 sup_reg[KW];
#pragma unroll
    for (int bi = 0; bi < KW; ++bi)
        sup_reg[bi] = supc[w * LSTRIDE + (bi << 6) + lane];  // bi>=w: unwritten, gated off
    u64 diagreg = supc[w * LSTRIDE + (w << 6) + lane];
    u64 nzmask = __ballot(diagreg != 0ull);

#pragma unroll
    for (int bi = 0; bi < KW; ++bi) {
        if (w == bi) {
            // serial greedy within word bi; only suppressor rows enter the loop
            u64 cur = keep_sh[bi];
            u64 active = cur & nzmask;
            while (active) {
                int i = __ffsll((long long)active) - 1;
                u64 wi = readlane64(diagreg, i);   // row i's mask (bits > i only)
                active &= active - 1;              // retire bit i
                cur &= ~wi;
                active &= ~wi;                     // suppressed rows can't suppress
            }
            if (lane == 0) { keep_sh[bi] = cur; acc_lds = cur; }
        }
        __syncthreads();
        if (w > bi) {
            u64 A = acc_lds;                       // accepted set of block bi
            u64 myv = sup_reg[bi];                 // row (bi*64+lane)'s mask over word w
            bool accb = ((A >> lane) & 1ull) != 0;
            u64 lanes = __ballot(accb && myv != 0ull);
            if (lanes) {                           // rare: sparse suppression
                u64 wred = 0;
                while (lanes) {
                    int l = __ffsll((long long)lanes) - 1;
                    wred |= readlane64(myv, l);
                    lanes &= lanes - 1;
                }
                if (lane == 0) keep_sh[w] &= ~wred;
            }
        }
        __syncthreads();
    }

    // ---- D: output ----
    if (tid < TOPK) {
        bool kp = ((keep_sh[w] >> lane) & 1ull) != 0;
        float o0 = 0.f, o1 = 0.f, o2 = 0.f, o3 = 0.f, o4 = 0.f, o6 = 0.f, o7 = 0.f, o8 = 0.f;
        if (kp) {
            u32 r = ~(u32)key;
            const float* p = pred + ((size_t)b * NPRED + r) * ROWF;
            float x = p[0], y = p[1], wd = p[2], hh = p[3];
            o0 = x - wd * 0.5f; o1 = y - hh * 0.5f;
            o2 = x + wd * 0.5f; o3 = y + hh * 0.5f;
            o4 = __uint_as_float((u32)(key >> 32));
            o6 = p[6]; o7 = p[7]; o8 = p[8];
        }
        size_t ob = ((size_t)b * TOPK + tid) * ROWF;
        out[ob + 0] = o0; out[ob + 1] = o1; out[ob + 2] = o2; out[ob + 3] = o3;
        out[ob + 4] = o4; out[ob + 5] = 0.f;
        out[ob + 6] = o6; out[ob + 7] = o7; out[ob + 8] = o8;
        keepout[(size_t)b * TOPK + tid] = kp ? 1.0f : 0.0f;
    }
}

extern "C" void kernel_launch(void* const* d_in, const int* in_sizes, int n_in,
                              void* d_out, int out_size, void* d_ws, size_t ws_size,
                              hipStream_t stream) {
    const float* pred = (const float*)d_in[0];
    float* out = (float*)d_out;                         // [32,1000,9]
    float* keepout = out + (size_t)BATCH * TOPK * ROWF; // [32,1000]
    char* ws = (char*)d_ws;
    u64* cand_ws = (u64*)(ws + WS_CAND);
    u64* tkey_ws = (u64*)(ws + WS_TKEY);

    compact_sort_kernel<<<BATCH * SUBS, 512, 0, stream>>>(pred, cand_ws, tkey_ws);
    rank_kernel<<<BATCH * SUBS, 512, 0, stream>>>(cand_ws, tkey_ws);
    supscan_kernel<<<BATCH, 1024, 0, stream>>>(pred, tkey_ws, out, keepout);
}

// Round 10
// 127.144 us; speedup vs baseline: 2.5014x; 1.7702x over previous
//
#include <hip/hip_runtime.h>
#include <stdint.h>

// Match reference numerics: no FMA contraction anywhere (discrete IoU>thres
// decisions flip on 1-ulp differences).
#pragma clang fp contract(off)

#define BATCH 32
#define NPRED 25200
#define ROWF 9
#define TOPK 1000
#define SUBS 8
#define ROWS_PER_SUB (NPRED / SUBS)   // 3150
#define SUBCAP 512
#define CONF_T 0.7f
#define IOU_T 0.45f
#define KW 16          // 1000 bits -> 16 u64 words
#define SUPROW 1024    // global sup stride per word-column
#define TKROW 1024     // tkey stride per image

typedef unsigned long long u64;
typedef unsigned int u32;

// ---- workspace layout (bytes) ----
#define WS_CAND 0                      // 256 lists x 512 u64 = 1,048,576
#define WS_TKEY (1048576)              // 32 x 1024 u64       =   262,144
#define WS_SUP  (WS_TKEY + 262144)     // 32 x 16 x 1024 u64  = 4,194,304

// Session notes baked in:
//  - R8: cooperative grid.sync costs ~60+ us/sync on this stack; never use it
//    where a ~6 us launch boundary suffices.
//  - R9: don't concentrate LDS-broadcast-heavy loops (supmat) onto 1 CU/image;
//    the per-CU LDS pipe serializes them. Keep supmat at 8 blocks/image.

__device__ __forceinline__ u64 readlane64(u64 v, int l) {
    // wave-uniform lane index -> v_readlane_b32 x2 (VALU, no LDS pipe)
    u32 lo = __builtin_amdgcn_readlane((u32)v, (u32)l);
    u32 hi = __builtin_amdgcn_readlane((u32)(v >> 32), (u32)l);
    return ((u64)hi << 32) | lo;
}

// K1: compact valid rows of one (image, sub-range) into keys, then bitonic-sort
// the 512-entry sub-list in-block (descending; zeros pad to the end).
// key = (float_bits(conf)<<32) | ~row  -> desc order == (score desc, idx asc),
// exactly jax.lax.top_k tie-breaking. ~317 valid rows per 3150 expected;
// SUBCAP=512 is mean+11.5 sigma. De-staged (R10): the test needs only cols
// 4,5 -> issue all ~14 scalar loads per thread up-front (independent, one
// waitcnt, latency-overlapped); no LDS row staging, no chunk barriers.
// Also zeroes this block's slice of tkey_ws (0xAA-poisoned).
__global__ __launch_bounds__(512) void compact_sort_kernel(const float* __restrict__ pred,
                                                           u64* __restrict__ cand_ws,
                                                           u64* __restrict__ tkey_ws) {
    __shared__ u64 skey[SUBCAP];          // 4096 B
    __shared__ u32 cnt;
    int bs = blockIdx.x;          // 0..255
    int b = bs >> 3, s = bs & 7;
    int tid = threadIdx.x;
    if (tid == 0) cnt = 0;
    skey[tid] = 0;
    if (tid < 128) tkey_ws[bs * 128 + tid] = 0;   // 256 blocks x 128 = 32 x 1024
    __syncthreads();

    // gather cols 4,5 for my rows: r = r0 + tid + k*512, k=0..6 (3150 = 6*512+78)
    int r0 = s * ROWS_PER_SUB;
    const int NCH = (ROWS_PER_SUB + 511) / 512;   // 7
    float objv[NCH], clsv[NCH];
#pragma unroll
    for (int k = 0; k < NCH; ++k) {
        int r = tid + k * 512;
        if (r < ROWS_PER_SUB) {
            size_t base = ((size_t)b * NPRED + r0 + r) * ROWF;
            objv[k] = pred[base + 4];
            clsv[k] = pred[base + 5];
        }
    }
#pragma unroll
    for (int k = 0; k < NCH; ++k) {
        int r = tid + k * 512;
        if (r < ROWS_PER_SUB) {
            float conf = objv[k] * clsv[k];
            if (objv[k] > CONF_T && conf > CONF_T) {
                int row = r0 + r;
                u32 slot = atomicAdd(&cnt, 1u);
                if (slot < SUBCAP)
                    skey[slot] = ((u64)__float_as_uint(conf) << 32) | (u64)(u32)(~(u32)row);
            }
        }
    }
    __syncthreads();
    // bitonic sort, descending, 512 elements, 512 threads (45 passes)
    for (int k = 2; k <= SUBCAP; k <<= 1) {
        for (int j = k >> 1; j > 0; j >>= 1) {
            int t = tid, p = t ^ j;
            if (p > t) {
                u64 a = skey[t], c2 = skey[p];
                bool desc = ((t & k) == 0);
                if (desc ? (a < c2) : (a > c2)) { skey[t] = c2; skey[p] = a; }
            }
            __syncthreads();
        }
    }
    cand_ws[(size_t)bs * SUBCAP + tid] = skey[tid];
}

// K2: rank, 8 blocks per image. Each block loads the image's full 8x512 key
// set and ranks its own sub-list's 512 keys: rank(key) = sum over all 8 lists
// of count(elements > key); own list's search returns the key's own index
// (keys unique). Breadth-interleaved pow2 ladder: 10 rounds x 8 independent
// LDS probes. Keys with rank < TOPK scatter to tkey_ws[b][rank].
__global__ __launch_bounds__(512) void rank_kernel(const u64* __restrict__ cand_ws,
                                                   u64* __restrict__ tkey_ws) {
    __shared__ u64 lists[SUBS * SUBCAP];   // 32 KB
    int bs = blockIdx.x;          // 0..255
    int b = bs >> 3, s = bs & 7;
    int tid = threadIdx.x;
    const u64* src = cand_ws + (size_t)b * SUBS * SUBCAP;
    for (int t = tid; t < SUBS * SUBCAP; t += 512) lists[t] = src[t];
    __syncthreads();
    u64 key = lists[(s << 9) + tid];
    if (key) {
        int lo[SUBS];
#pragma unroll
        for (int l = 0; l < SUBS; ++l) lo[l] = 0;
#pragma unroll
        for (int w2 = SUBCAP; w2 >= 1; w2 >>= 1) {   // 10 rounds
#pragma unroll
            for (int l = 0; l < SUBS; ++l) {
                int p = lo[l] + w2;
                if (p <= SUBCAP && lists[(l << 9) + p - 1] > key) lo[l] = p;
            }
        }
        int rank = 0;
#pragma unroll
        for (int l = 0; l < SUBS; ++l) rank += lo[l];
        if (rank < TOPK) tkey_ws[(size_t)b * TKROW + rank] = key;
    }
}

// K3: suppression matrix as 136 upper-triangle 64x64 tiles per image,
// one tile per wave (8 blocks/image x 16 waves). Gathers pred rows from
// tkey_ws itself (deterministic recompute; identical FP expressions).
// j is wave-uniform -> LDS broadcast reads; word accumulates in a register.
__global__ __launch_bounds__(1024) void supmat_kernel(const float* __restrict__ pred,
                                                      const u64* __restrict__ tkey_ws,
                                                      u64* __restrict__ sup_g) {
    __shared__ float4 bx_s[TOPK];   // 16 KB
    __shared__ float  ar_s[TOPK];   // 4 KB
    int b = blockIdx.x >> 3, q = blockIdx.x & 7;
    int tid = threadIdx.x;
    if (tid < TOPK) {
        u64 key = tkey_ws[(size_t)b * TKROW + tid];
        float4 box = make_float4(0.f, 0.f, 0.f, 0.f);
        float ar = 0.f;
        if (key) {
            u32 r = ~(u32)key;
            const float* p = pred + ((size_t)b * NPRED + r) * ROWF;
            float x = p[0], y = p[1], w = p[2], hh = p[3];
            box = make_float4(x - w * 0.5f, y - hh * 0.5f, x + w * 0.5f, y + hh * 0.5f);
            ar = (box.z - box.x) * (box.w - box.y);
        }
        bx_s[tid] = box; ar_s[tid] = ar;
    }
    __syncthreads();
    int wave = tid >> 6, lane = tid & 63;
    for (int pass = 0; pass < 2; ++pass) {
        int t = (pass == 0) ? (q * 16 + wave) : ((wave == 15) ? 128 + q : 136);
        if (t >= 136) continue;
        // decode tile t -> (iw, jw), jw >= iw
        int iw = 0, rem = t, c = 16;
        while (rem >= c) { rem -= c; c--; iw++; }
        int jw = iw + rem;
        int i = iw * 64 + lane;
        bool act = i < TOPK;
        float4 bi = act ? bx_s[i] : make_float4(0.f, 0.f, 0.f, 0.f);
        float ai = act ? ar_s[i] : 0.f;
        u64 m = 0;
        int jbase = jw << 6;
        int jend = jbase + 64; if (jend > TOPK) jend = TOPK;
        for (int j = jbase; j < jend; ++j) {
            float4 bj = bx_s[j];            // broadcast
            float aj = ar_s[j];             // broadcast
            float lx = fmaxf(bi.x, bj.x);
            float ly = fmaxf(bi.y, bj.y);
            float rx = fminf(bi.z, bj.z);
            float ry = fminf(bi.w, bj.w);
            float iw2 = rx - lx; iw2 = iw2 > 0.f ? iw2 : 0.f;
            float ih = ry - ly; ih = ih > 0.f ? ih : 0.f;
            float inter = iw2 * ih;
            float den = ai + aj - inter + 1e-7f;  // ((ai+aj)-inter)+eps, ref order
            float iou = inter / den;
            if (act && j > i && iou > IOU_T) m |= 1ull << (j - jbase);
        }
        if (act) sup_g[((size_t)b * KW + jw) * SUPROW + i] = m;
    }
}

// K4: sparse register-resident greedy scan + output. keep0 from key!=0 via
// ballot; score from key bits; pred gathered only for kept rows. Serial loop
// only visits rows that actually suppress (ballot-gated); uniform broadcasts
// via v_readlane (VALU, no LDS pipe in the chain).
__global__ __launch_bounds__(1024) void scan_out_kernel(const float* __restrict__ pred,
                                                        const u64* __restrict__ tkey_ws,
                                                        const u64* __restrict__ sup_g,
                                                        float* __restrict__ out,
                                                        float* __restrict__ keepout) {
    __shared__ u64 keep_lds[KW];
    __shared__ u64 acc_lds;
    int b = blockIdx.x, tid = threadIdx.x;
    int w = tid >> 6, lane = tid & 63;
    const u64* S = sup_g + (size_t)b * KW * SUPROW;

    u64 key = tkey_ws[(size_t)b * TKROW + tid];   // slots >= TOPK are zero
    u64 keep0 = __ballot(key != 0ull);            // row w*64+lane
    if (lane == 0) keep_lds[w] = keep0;

    u64 sup_reg[KW];
    u64 diagreg = 0;
#pragma unroll
    for (int bi = 0; bi < KW; ++bi) {
        sup_reg[bi] = S[(size_t)w * SUPROW + (bi << 6) + lane]; // bi>w: garbage, never used
        if (bi == w) diagreg = sup_reg[bi];
    }
    __syncthreads();

    u64 nzmask = __ballot(diagreg != 0);   // rows of this word with in-word suppression

#pragma unroll
    for (int bi = 0; bi < KW; ++bi) {
        if (w == bi) {
            // serial greedy within word bi; only suppressor rows enter the loop
            u64 cur = keep_lds[bi];
            u64 active = cur & nzmask;
            while (active) {
                int i = __ffsll((long long)active) - 1;
                u64 wi = readlane64(diagreg, i);   // row i's mask (bits > i only)
                active &= active - 1;              // retire bit i
                cur &= ~wi;
                active &= ~wi;                     // suppressed rows can't suppress
            }
            if (lane == 0) { keep_lds[bi] = cur; acc_lds = cur; }
        }
        __syncthreads();
        if (w > bi) {
            u64 A = acc_lds;                       // accepted set of block bi
            u64 myv = sup_reg[bi];                 // row (bi*64+lane)'s mask over word w
            bool accb = (A >> lane) & 1ull;
            u64 lanes = __ballot(accb && myv != 0ull);
            if (lanes) {                           // rare: sparse suppression
                u64 wred = 0;
                while (lanes) {
                    int l = __ffsll((long long)lanes) - 1;
                    wred |= readlane64(myv, l);
                    lanes &= lanes - 1;
                }
                if (lane == 0) keep_lds[w] &= ~wred;
            }
        }
        __syncthreads();
    }

    if (tid < TOPK) {
        bool kp = ((keep_lds[w] >> lane) & 1ull) != 0;
        float o0 = 0.f, o1 = 0.f, o2 = 0.f, o3 = 0.f, o4 = 0.f, o6 = 0.f, o7 = 0.f, o8 = 0.f;
        if (kp) {
            u32 r = ~(u32)key;
            const float* p = pred + ((size_t)b * NPRED + r) * ROWF;
            float x = p[0], y = p[1], wd = p[2], hh = p[3];
            o0 = x - wd * 0.5f; o1 = y - hh * 0.5f;
            o2 = x + wd * 0.5f; o3 = y + hh * 0.5f;
            o4 = __uint_as_float((u32)(key >> 32));
            o6 = p[6]; o7 = p[7]; o8 = p[8];
        }
        size_t ob = ((size_t)b * TOPK + tid) * ROWF;
        out[ob + 0] = o0; out[ob + 1] = o1; out[ob + 2] = o2; out[ob + 3] = o3;
        out[ob + 4] = o4; out[ob + 5] = 0.f;
        out[ob + 6] = o6; out[ob + 7] = o7; out[ob + 8] = o8;
        keepout[(size_t)b * TOPK + tid] = kp ? 1.0f : 0.0f;
    }
}

extern "C" void kernel_launch(void* const* d_in, const int* in_sizes, int n_in,
                              void* d_out, int out_size, void* d_ws, size_t ws_size,
                              hipStream_t stream) {
    const float* pred = (const float*)d_in[0];
    float* out = (float*)d_out;                         // [32,1000,9]
    float* keepout = out + (size_t)BATCH * TOPK * ROWF; // [32,1000]
    char* ws = (char*)d_ws;
    u64* cand_ws = (u64*)(ws + WS_CAND);
    u64* tkey_ws = (u64*)(ws + WS_TKEY);
    u64* sup_g = (u64*)(ws + WS_SUP);

    compact_sort_kernel<<<BATCH * SUBS, 512, 0, stream>>>(pred, cand_ws, tkey_ws);
    rank_kernel<<<BATCH * SUBS, 512, 0, stream>>>(cand_ws, tkey_ws);
    supmat_kernel<<<BATCH * SUBS, 1024, 0, stream>>>(pred, tkey_ws, sup_g);
    scan_out_kernel<<<BATCH, 1024, 0, stream>>>(pred, tkey_ws, sup_g, out, keepout);
}